// Round 8
// baseline (506.342 us; speedup 1.0000x reference)
//
#include <hip/hip_runtime.h>
#include <hip/hip_bf16.h>

typedef __hip_bfloat16 bf16;
typedef __attribute__((ext_vector_type(8))) short short8;
typedef __attribute__((ext_vector_type(4))) short short4v;
typedef __attribute__((ext_vector_type(4))) float float4v;

__device__ __forceinline__ short f2bs(float x) {
    bf16 b = __float2bfloat16(x);
    return *reinterpret_cast<short*>(&b);
}

// wave-local LDS fence: order ds_write -> ds_read within one wave without a
// workgroup barrier (zs regions are wave-private in disco_k).
__device__ __forceinline__ void wave_lds_fence() {
    __builtin_amdgcn_wave_barrier();
    __builtin_amdgcn_s_waitcnt(0xC07F);   // lgkmcnt(0), vmcnt/expcnt untouched
    __builtin_amdgcn_wave_barrier();
}

// ---------------------------------------------------------------------------
// Bilinear 2x upsample + pack with elev: out2[i] = {upsampled(i), elev(i)}.
// ---------------------------------------------------------------------------
__global__ void upsample_pack_k(const float* __restrict__ in,
                                const float* __restrict__ elev,
                                float* __restrict__ out2, int B, int H, int W) {
    const int OH = 2 * H, OW = 2 * W;
    const long total = (long)B * OH * OW;
    long i = (long)blockIdx.x * blockDim.x + threadIdx.x;
    if (i >= total) return;
    int ox = (int)(i % OW);
    long r = i / OW;
    int oy = (int)(r % OH);
    int b  = (int)(r / OH);
    float sy = fminf(fmaxf(oy * 0.5f - 0.25f, 0.0f), (float)(H - 1));
    float sx = fminf(fmaxf(ox * 0.5f - 0.25f, 0.0f), (float)(W - 1));
    int y0 = (int)sy; float ty = sy - (float)y0; int y1 = min(y0 + 1, H - 1);
    int x0 = (int)sx; float tx = sx - (float)x0; int x1 = min(x0 + 1, W - 1);
    const float* p = in + (size_t)b * H * W;
    float v00 = p[(size_t)y0 * W + x0];
    float v01 = p[(size_t)y0 * W + x1];
    float v10 = p[(size_t)y1 * W + x0];
    float v11 = p[(size_t)y1 * W + x1];
    float v = (v00 * (1.f - ty) + v10 * ty) * (1.f - tx)
            + (v01 * (1.f - ty) + v11 * ty) * tx;
    float2 o; o.x = v; o.y = elev[i];
    *(float2*)(out2 + i * 2) = o;
}

// ---------------------------------------------------------------------------
// Fused weight packs (all six arrays in one launch). Layouts as round 5.
// ---------------------------------------------------------------------------
__global__ void packall_k(const float* __restrict__ cw2_1, const float* __restrict__ cw2_2,
                          const float* __restrict__ cw3_1, const float* __restrict__ cw3_2,
                          const float* __restrict__ w1,    const float* __restrict__ w2,
                          short* __restrict__ wfA,  short* __restrict__ wfB,
                          short* __restrict__ wf31, short* __restrict__ wf32,
                          short* __restrict__ wfD1, short* __restrict__ wfD2) {
    int gi = blockIdx.x * 256 + threadIdx.x;
    if (gi < 102400) {
        const float* src = (gi < 51200) ? cw2_1 : cw2_2;
        short* dst       = (gi < 51200) ? wfA   : wfB;
        int i = (gi < 51200) ? gi : gi - 51200;
        int j    = i & 7;
        int r    = i >> 3;
        int lane = r & 63;
        int r2   = r >> 6;
        int mt   = r2 & 1;
        int r3   = r2 >> 1;
        int tap  = r3 % 25;
        int icc  = r3 / 25;
        int m = lane & 15, q = lane >> 4;
        int oc = mt * 16 + m;
        int ic = icc * 32 + q * 8 + j;
        dst[i] = f2bs(src[((size_t)oc * 64 + ic) * 25 + tap]);
    } else if (gi < 128000) {
        int gi2 = gi - 102400;
        const float* src = (gi2 < 12800) ? cw3_1 : cw3_2;
        short* dst       = (gi2 < 12800) ? wf31  : wf32;
        int i = (gi2 < 12800) ? gi2 : gi2 - 12800;
        int j    = i & 7;
        int r    = i >> 3;
        int lane = r & 63;
        int tap  = r >> 6;
        int m = lane & 15, q = lane >> 4;
        dst[i] = (m == 0) ? f2bs(src[(size_t)(q * 8 + j) * 25 + tap]) : (short)0;
    } else if (gi < 132096) {
        int gi2 = gi - 128000;
        const float* src = (gi2 < 2048) ? w1 : w2;
        short* dst       = (gi2 < 2048) ? wfD1 : wfD2;
        int i = (gi2 < 2048) ? gi2 : gi2 - 2048;
        int j = i & 7;
        int r = i >> 3;
        int lane = r & 63;
        int mtile = r >> 6;
        int q = lane >> 4, mm = lane & 15;
        int oc = mtile * 16 + mm;
        int k = q * 8 + j;
        dst[i] = (k < 18) ? f2bs(src[oc * 18 + k]) : (short)0;
    }
}

// ---------------------------------------------------------------------------
// disco conv with MFMA output matmul. Batch handling is parameterized:
// processes nb batches starting at blockIdx.y*nb (stage 1: nb=1 and gridDim.y
// =4 for CU utilization at small P; stage 2: nb=4, psi regs reused 4x).
// One fence per batch: z ds_writes -> bz ds_reads. The former second fence
// (bz reads vs next batch z writes) is redundant: same-wave LDS ops to
// may-aliasing addresses issue and execute in order.
// ---------------------------------------------------------------------------
__global__ __launch_bounds__(256)
void disco_k(const float* __restrict__ ui,
             const int* __restrict__ psi_idx, const float* __restrict__ psi_val,
             const short* __restrict__ wfragD, const float* __restrict__ bias,
             short* __restrict__ outh, int P, int nb) {
    __shared__ short zs[256 * 40];
    const int tid  = threadIdx.x;
    const int lane = tid & 63;
    const int wv   = tid >> 6;
    const int q    = lane >> 4;
    const int n    = lane & 15;

    for (int c0 = 0; c0 < 40; c0 += 8) *(short8*)(zs + tid * 40 + c0) = (short8)0;

    short8 af[4];
    float brg[4][4];
    #pragma unroll
    for (int mt = 0; mt < 4; mt++) {
        af[mt] = *(const short8*)(wfragD + ((mt * 64 + lane) << 3));
        #pragma unroll
        for (int r = 0; r < 4; r++) brg[mt][r] = bias[mt * 16 + q * 4 + r];
    }

    const int p = blockIdx.x * 256 + tid;
    const bool valid = p < P;
    const int bq0 = blockIdx.y * nb;

    int idx[8];
    float pv[9][8];
    if (valid) {
        const int* ip = psi_idx + (size_t)p * 8;
        int4 ia = *(const int4*)ip;
        int4 ib = *(const int4*)(ip + 4);
        idx[0]=ia.x; idx[1]=ia.y; idx[2]=ia.z; idx[3]=ia.w;
        idx[4]=ib.x; idx[5]=ib.y; idx[6]=ib.z; idx[7]=ib.w;
        #pragma unroll
        for (int k = 0; k < 9; k++) {
            const float* qp = psi_val + ((size_t)k * P + p) * 8;
            float4 qa = *(const float4*)qp;
            float4 qb = *(const float4*)(qp + 4);
            pv[k][0]=qa.x; pv[k][1]=qa.y; pv[k][2]=qa.z; pv[k][3]=qa.w;
            pv[k][4]=qb.x; pv[k][5]=qb.y; pv[k][6]=qb.z; pv[k][7]=qb.w;
        }
    }

    for (int bi = 0; bi < nb; bi++) {
        const int bq = bq0 + bi;
        if (valid) {
            const float* ub = ui + (size_t)bq * P * 2;
            float g0[8], g1[8];
            #pragma unroll
            for (int t = 0; t < 8; t++) {
                float2 g = *(const float2*)(ub + (size_t)idx[t] * 2);
                g0[t] = g.x; g1[t] = g.y;
            }
            float z[18];
            #pragma unroll
            for (int j = 0; j < 18; j++) z[j] = 0.f;
            #pragma unroll
            for (int k = 0; k < 9; k++) {
                #pragma unroll
                for (int t = 0; t < 8; t++) {
                    z[k]     = fmaf(g0[t], pv[k][t], z[k]);
                    z[9 + k] = fmaf(g1[t], pv[k][t], z[9 + k]);
                }
            }
            #pragma unroll
            for (int c0i = 0; c0i < 16; c0i += 4) {
                short4v t4;
                t4.x = f2bs(z[c0i]); t4.y = f2bs(z[c0i+1]);
                t4.z = f2bs(z[c0i+2]); t4.w = f2bs(z[c0i+3]);
                *(short4v*)(zs + tid * 40 + c0i) = t4;
            }
            unsigned int lo = (unsigned short)f2bs(z[16]);
            unsigned int hi = (unsigned short)f2bs(z[17]);
            *(unsigned int*)(zs + tid * 40 + 16) = lo | (hi << 16);
        }
        wave_lds_fence();     // z writes (own wave) -> bz reads (own wave)

        #pragma unroll
        for (int t = 0; t < 4; t++) {
            const int nt  = wv * 4 + t;
            const int pix = blockIdx.x * 256 + nt * 16 + n;
            short8 bz = *(const short8*)(zs + (nt * 16 + n) * 40 + q * 8);
            const bool pok = pix < P;
            short* hp = outh + ((size_t)bq * P + pix) * 64;
            #pragma unroll
            for (int mt = 0; mt < 4; mt++) {
                float4v acc = {0.f, 0.f, 0.f, 0.f};
                acc = __builtin_amdgcn_mfma_f32_16x16x32_bf16(af[mt], bz, acc, 0, 0, 0);
                if (pok) {
                    short4v o;
                    o.x = f2bs(fmaxf(acc.x + brg[mt][0], 0.f));
                    o.y = f2bs(fmaxf(acc.y + brg[mt][1], 0.f));
                    o.z = f2bs(fmaxf(acc.z + brg[mt][2], 0.f));
                    o.w = f2bs(fmaxf(acc.w + brg[mt][3], 0.f));
                    *(short4v*)(hp + mt * 16 + q * 4) = o;
                }
            }
        }
        // no second fence: next batch's z ds_writes cannot pass this batch's
        // bz ds_reads (same wave, in-order DS, may-alias addresses)
    }
}

// ---------------------------------------------------------------------------
// conv2 implicit-GEMM MFMA, 2 output rows per wave, 32px x 8row tile.
// Slab [12 rows][36 cols][40 kslots] bf16 = 34,560 B.
// kx-outer with double-buffered weight register file (round 7).
// launch_bounds(256,4): measured VGPR=72 fits the 128-cap; restores the
// 4-blocks/CU occupancy that round 6 showed this kernel responds to.
// ---------------------------------------------------------------------------
__global__ __launch_bounds__(256, 4)
void conv2_k(const short* __restrict__ hS, const short* __restrict__ wfrag,
             const float* __restrict__ bias, short* __restrict__ outc,
             int H, int W) {
    __shared__ short slab[12 * 36 * 40];   // 34,560 B
    const int tid  = threadIdx.x;
    const int wv   = tid >> 6;
    const int lane = tid & 63;
    const int q    = lane >> 4;
    const int n    = lane & 15;
    const int xbase = blockIdx.x * 32;
    const int ybase = blockIdx.y * 8;
    const int b     = blockIdx.z;
    const short* hb = hS + (size_t)b * H * W * 64;

    float4v acc[2][2][2];   // [row][nt][mt]
    #pragma unroll
    for (int ri = 0; ri < 2; ri++)
        #pragma unroll
        for (int nt = 0; nt < 2; nt++)
            #pragma unroll
            for (int mt = 0; mt < 2; mt++)
                acc[ri][nt][mt] = (float4v){0.f, 0.f, 0.f, 0.f};

    float brg[2][4];
    #pragma unroll
    for (int mt = 0; mt < 2; mt++)
        #pragma unroll
        for (int r = 0; r < 4; r++) brg[mt][r] = bias[mt * 16 + q * 4 + r];

    for (int icc = 0; icc < 2; icc++) {
        const short* wfr = wfrag + (size_t)icc * 25600;
        short8 wbuf[2][5][2];
        // prologue: kx=0 column, issued before the staging barrier
        #pragma unroll
        for (int ky = 0; ky < 5; ky++) {
            wbuf[0][ky][0] = *(const short8*)(wfr + (((ky * 5) * 2 + 0) * 64 + lane) * 8);
            wbuf[0][ky][1] = *(const short8*)(wfr + (((ky * 5) * 2 + 1) * 64 + lane) * 8);
        }
        __syncthreads();
        for (int l = tid; l < 1728; l += 256) {      // 12*36*4 16B-chunks
            int qq  = l & 3;
            int pix = l >> 2;            // row*36+col
            int row = pix / 36;
            int col = pix - row * 36;
            int gy = ybase - 2 + row;
            int gx = xbase - 2 + col;
            short8 v = (short8)0;
            if ((unsigned)gy < (unsigned)H && (unsigned)gx < (unsigned)W)
                v = *(const short8*)(hb + ((size_t)gy * W + gx) * 64 + icc * 32 + qq * 8);
            *(short8*)(slab + pix * 40 + qq * 8) = v;
        }
        __syncthreads();

        #pragma unroll
        for (int kx = 0; kx < 5; kx++) {
            const int cur = kx & 1;
            if (kx < 4) {   // prefetch next kx column into the other buffer
                #pragma unroll
                for (int ky = 0; ky < 5; ky++) {
                    wbuf[cur ^ 1][ky][0] = *(const short8*)(wfr + (((ky * 5 + kx + 1) * 2 + 0) * 64 + lane) * 8);
                    wbuf[cur ^ 1][ky][1] = *(const short8*)(wfr + (((ky * 5 + kx + 1) * 2 + 1) * 64 + lane) * 8);
                }
            }
            #pragma unroll
            for (int t = 0; t < 6; t++) {
                const int boff = ((wv * 2 + t) * 36 + n + kx) * 40 + q * 8;
                short8 b0 = *(const short8*)(slab + boff);
                short8 b1 = *(const short8*)(slab + boff + 640);
                if (t <= 4) {   // row0: tap (ky=t, kx)
                    acc[0][0][0] = __builtin_amdgcn_mfma_f32_16x16x32_bf16(wbuf[cur][t][0], b0, acc[0][0][0], 0, 0, 0);
                    acc[0][0][1] = __builtin_amdgcn_mfma_f32_16x16x32_bf16(wbuf[cur][t][1], b0, acc[0][0][1], 0, 0, 0);
                    acc[0][1][0] = __builtin_amdgcn_mfma_f32_16x16x32_bf16(wbuf[cur][t][0], b1, acc[0][1][0], 0, 0, 0);
                    acc[0][1][1] = __builtin_amdgcn_mfma_f32_16x16x32_bf16(wbuf[cur][t][1], b1, acc[0][1][1], 0, 0, 0);
                }
                if (t >= 1) {   // row1: tap (ky=t-1, kx) — same regs, no reload
                    acc[1][0][0] = __builtin_amdgcn_mfma_f32_16x16x32_bf16(wbuf[cur][t - 1][0], b0, acc[1][0][0], 0, 0, 0);
                    acc[1][0][1] = __builtin_amdgcn_mfma_f32_16x16x32_bf16(wbuf[cur][t - 1][1], b0, acc[1][0][1], 0, 0, 0);
                    acc[1][1][0] = __builtin_amdgcn_mfma_f32_16x16x32_bf16(wbuf[cur][t - 1][0], b1, acc[1][1][0], 0, 0, 0);
                    acc[1][1][1] = __builtin_amdgcn_mfma_f32_16x16x32_bf16(wbuf[cur][t - 1][1], b1, acc[1][1][1], 0, 0, 0);
                }
            }
        }
    }

    #pragma unroll
    for (int ri = 0; ri < 2; ri++) {
        const int y = ybase + wv * 2 + ri;
        if (y < H) {
            #pragma unroll
            for (int nt = 0; nt < 2; nt++) {
                const int x = xbase + nt * 16 + n;
                if (x < W) {
                    short* cp = outc + (((size_t)b * H * W + (size_t)y * W + x) * 32);
                    #pragma unroll
                    for (int mt = 0; mt < 2; mt++) {
                        short4v o;
                        o.x = f2bs(fmaxf(acc[ri][nt][mt].x + brg[mt][0], 0.f));
                        o.y = f2bs(fmaxf(acc[ri][nt][mt].y + brg[mt][1], 0.f));
                        o.z = f2bs(fmaxf(acc[ri][nt][mt].z + brg[mt][2], 0.f));
                        o.w = f2bs(fmaxf(acc[ri][nt][mt].w + brg[mt][3], 0.f));
                        *(short4v*)(cp + mt * 16 + q * 4) = o;
                    }
                }
            }
        }
    }
}

// ---------------------------------------------------------------------------
// conv3 implicit-GEMM MFMA, 2 output rows per wave, 32px x 8row tile.
// IC=32 -> OC=1 (M padded to 16), +bias. Slab [12][36][40] = 34,560 B.
// ---------------------------------------------------------------------------
__global__ __launch_bounds__(256, 4)
void conv3_k(const short* __restrict__ cP, const short* __restrict__ wf3,
             const float* __restrict__ bias, float* __restrict__ out,
             int H, int W) {
    __shared__ short slab[12 * 36 * 40];
    const int tid  = threadIdx.x;
    const int wv   = tid >> 6;
    const int lane = tid & 63;
    const int q    = lane >> 4;
    const int n    = lane & 15;
    const int xbase = blockIdx.x * 32;
    const int ybase = blockIdx.y * 8;
    const int b     = blockIdx.z;
    const short* cb = cP + (size_t)b * H * W * 32;

    short8 wbuf[2][5];
    #pragma unroll
    for (int ky = 0; ky < 5; ky++)
        wbuf[0][ky] = *(const short8*)(wf3 + (((ky * 5) * 64 + lane)) * 8);

    for (int l = tid; l < 1728; l += 256) {
        int qq  = l & 3;
        int pix = l >> 2;
        int row = pix / 36;
        int col = pix - row * 36;
        int gy = ybase - 2 + row;
        int gx = xbase - 2 + col;
        short8 v = (short8)0;
        if ((unsigned)gy < (unsigned)H && (unsigned)gx < (unsigned)W)
            v = *(const short8*)(cb + ((size_t)gy * W + gx) * 32 + qq * 8);
        *(short8*)(slab + pix * 40 + qq * 8) = v;
    }
    __syncthreads();

    float4v acc[2][2];
    #pragma unroll
    for (int ri = 0; ri < 2; ri++)
        #pragma unroll
        for (int nt = 0; nt < 2; nt++) acc[ri][nt] = (float4v){0.f, 0.f, 0.f, 0.f};

    #pragma unroll
    for (int kx = 0; kx < 5; kx++) {
        const int cur = kx & 1;
        if (kx < 4) {
            #pragma unroll
            for (int ky = 0; ky < 5; ky++)
                wbuf[cur ^ 1][ky] = *(const short8*)(wf3 + (((ky * 5 + kx + 1) * 64 + lane)) * 8);
        }
        #pragma unroll
        for (int t = 0; t < 6; t++) {
            const int boff = ((wv * 2 + t) * 36 + n + kx) * 40 + q * 8;
            short8 b0 = *(const short8*)(slab + boff);
            short8 b1 = *(const short8*)(slab + boff + 640);
            if (t <= 4) {
                acc[0][0] = __builtin_amdgcn_mfma_f32_16x16x32_bf16(wbuf[cur][t], b0, acc[0][0], 0, 0, 0);
                acc[0][1] = __builtin_amdgcn_mfma_f32_16x16x32_bf16(wbuf[cur][t], b1, acc[0][1], 0, 0, 0);
            }
            if (t >= 1) {
                acc[1][0] = __builtin_amdgcn_mfma_f32_16x16x32_bf16(wbuf[cur][t - 1], b0, acc[1][0], 0, 0, 0);
                acc[1][1] = __builtin_amdgcn_mfma_f32_16x16x32_bf16(wbuf[cur][t - 1], b1, acc[1][1], 0, 0, 0);
            }
        }
    }

    const float bi = bias[0];
    if (q == 0) {
        #pragma unroll
        for (int ri = 0; ri < 2; ri++) {
            const int y = ybase + wv * 2 + ri;
            if (y < H) {
                #pragma unroll
                for (int nt = 0; nt < 2; nt++) {
                    const int x = xbase + nt * 16 + n;
                    if (x < W) out[((size_t)b * H + y) * W + x] = acc[ri][nt].x + bi;
                }
            }
        }
    }
}

// ---------------------------------------------------------------------------
extern "C" void kernel_launch(void* const* d_in, const int* in_sizes, int n_in,
                              void* d_out, int out_size, void* d_ws, size_t ws_size,
                              hipStream_t stream) {
    const float* x        = (const float*)d_in[0];
    const float* elev0    = (const float*)d_in[1];
    const float* elev1    = (const float*)d_in[2];
    const int*   psi_idx1 = (const int*)  d_in[3];
    const float* psi_val1 = (const float*)d_in[4];
    const float* w1       = (const float*)d_in[5];
    const float* b1       = (const float*)d_in[6];
    const float* cw2_1    = (const float*)d_in[7];
    const float* cb2_1    = (const float*)d_in[8];
    const float* cw3_1    = (const float*)d_in[9];
    const float* cb3_1    = (const float*)d_in[10];
    const int*   psi_idx2 = (const int*)  d_in[11];
    const float* psi_val2 = (const float*)d_in[12];
    const float* w2       = (const float*)d_in[13];
    const float* b2       = (const float*)d_in[14];
    const float* cw2_2    = (const float*)d_in[15];
    const float* cb2_2    = (const float*)d_in[16];
    const float* cw3_2    = (const float*)d_in[17];
    const float* cb3_2    = (const float*)d_in[18];

    const int B = 4;
    const int H1 = 180, W1 = 360, P1 = H1 * W1;
    const int H2 = 360, W2 = 720, P2 = H2 * W2;

    // workspace layout (bytes); u2i overlaps the tail of c (stage-1 c uses
    // only the first 16.6 MB; u2i is dead before conv2_2 rewrites c).
    char* ws = (char*)d_ws;
    short* h    = (short*)(ws);                      // 132,710,400
    short* c    = (short*)(ws + 132710400);          //  66,355,200
    float* u2i  = (float*)(ws + 149299200);          //   8,294,400 (inside c tail)
    float* u1i  = (float*)(ws + 199065600);          //   2,073,600
    float* s1   = (float*)(ws + 201139200);          //   1,036,800
    short* wfA  = (short*)(ws + 202176000);          //     102,400
    short* wfB  = (short*)(ws + 202278400);          //     102,400
    short* wfD1 = (short*)(ws + 202380800);          //       4,096
    short* wfD2 = (short*)(ws + 202384896);          //       4,096
    short* wf31 = (short*)(ws + 202388992);          //      25,600
    short* wf32 = (short*)(ws + 202414592);          //      25,600
    (void)ws_size; (void)in_sizes; (void)n_in; (void)out_size;

    packall_k<<<(132096 + 255) / 256, 256, 0, stream>>>(
        cw2_1, cw2_2, cw3_1, cw3_2, w1, w2, wfA, wfB, wf31, wf32, wfD1, wfD2);

    // ---- stage 1 ----
    upsample_pack_k<<<(B * P1 + 255) / 256, 256, 0, stream>>>(x, elev0, u1i, B, 90, 180);
    disco_k<<<dim3((P1 + 255) / 256, 4), 256, 0, stream>>>(
        u1i, psi_idx1, psi_val1, wfD1, b1, h, P1, 1);   // batch-per-block: small grid
    conv2_k<<<dim3((W1 + 31) / 32, (H1 + 7) / 8, B), 256, 0, stream>>>(
        h, wfA, cb2_1, c, H1, W1);
    conv3_k<<<dim3((W1 + 31) / 32, (H1 + 7) / 8, B), 256, 0, stream>>>(
        c, wf31, cb3_1, s1, H1, W1);

    // ---- stage 2 ----
    upsample_pack_k<<<(B * P2 + 255) / 256, 256, 0, stream>>>(s1, elev1, u2i, B, H1, W1);
    disco_k<<<dim3((P2 + 255) / 256, 1), 256, 0, stream>>>(
        u2i, psi_idx2, psi_val2, wfD2, b2, h, P2, 4);   // psi regs reused 4x
    conv2_k<<<dim3((W2 + 31) / 32, (H2 + 7) / 8, B), 256, 0, stream>>>(
        h, wfB, cb2_2, c, H2, W2);
    conv3_k<<<dim3((W2 + 31) / 32, (H2 + 7) / 8, B), 256, 0, stream>>>(
        c, wf32, cb3_2, (float*)d_out, H2, W2);
}